// Round 6
// baseline (3736.698 us; speedup 1.0000x reference)
//
#include <hip/hip_runtime.h>
#include <hip/hip_bf16.h>

typedef unsigned short u16;
typedef __attribute__((ext_vector_type(8))) __bf16 bf16x8;   // MFMA A/B frag (4 VGPRs)
typedef __attribute__((ext_vector_type(4))) float f32x4;     // MFMA C/D frag
typedef __attribute__((ext_vector_type(4))) unsigned short u16x4;

#define EMB   1024
#define HEADS 16
#define HD    64
#define BATCH 2
#define SEQ   4096

static __device__ inline u16 f2bf(float f) {
    __bf16 b = (__bf16)f;                 // RNE fptrunc
    return __builtin_bit_cast(unsigned short, b);
}
static __device__ inline float bflo(unsigned w) {            // low u16 -> f32
    return __builtin_bit_cast(float, w << 16);
}
static __device__ inline float bfhi(unsigned w) {            // high u16 -> f32
    return __builtin_bit_cast(float, w & 0xFFFF0000u);
}

// ---------------- fused convert + QKV projection GEMM: Y = X @ W^T ----------
// UNCHANGED from round 2/4 (isomorphic to guide's m92/m97 verified structure).
// z=0: Q -> fp32 into d_out ([B,T,C]); z=1: K bf16 [B,H,T,D]; z=2: V bf16.
__global__ void __launch_bounds__(256) gemm_qkv(
        const float* __restrict__ X,
        const float* __restrict__ Wq, const float* __restrict__ Wk, const float* __restrict__ Wv,
        float* __restrict__ Qf, u16* __restrict__ Kb, u16* __restrict__ Vb) {
    const int z = blockIdx.z;
    const float* W = (z == 0) ? Wq : (z == 1 ? Wk : Wv);

    __shared__ u16 As[128][40];
    __shared__ u16 Bs[128][40];

    const int tid = threadIdx.x, lane = tid & 63, wave = tid >> 6;
    const int wr = wave >> 1, wc = wave & 1;
    const int m0 = blockIdx.y * 128, n0 = blockIdx.x * 128;
    const int lrow = lane & 15, lkg = lane >> 4, lk = lkg * 8;

    f32x4 acc[4][4];
#pragma unroll
    for (int i = 0; i < 4; ++i)
#pragma unroll
        for (int j = 0; j < 4; ++j) acc[i][j] = {};

    for (int k0 = 0; k0 < EMB; k0 += 32) {
        __syncthreads();
#pragma unroll
        for (int p = 0; p < 4; ++p) {
            int c = tid + p * 256;
            int row = c >> 3, col = (c & 7) * 4;
            float4 xa = *reinterpret_cast<const float4*>(X + (long)(m0 + row) * EMB + k0 + col);
            u16x4 xo = { f2bf(xa.x), f2bf(xa.y), f2bf(xa.z), f2bf(xa.w) };
            *reinterpret_cast<u16x4*>(&As[row][col]) = xo;
            float4 wa = *reinterpret_cast<const float4*>(W + (long)(n0 + row) * EMB + k0 + col);
            u16x4 wo = { f2bf(wa.x), f2bf(wa.y), f2bf(wa.z), f2bf(wa.w) };
            *reinterpret_cast<u16x4*>(&Bs[row][col]) = wo;
        }
        __syncthreads();

        bf16x8 af[4], bfr[4];
#pragma unroll
        for (int i = 0; i < 4; ++i)
            af[i] = *reinterpret_cast<const bf16x8*>(&As[wr * 64 + i * 16 + lrow][lk]);
#pragma unroll
        for (int j = 0; j < 4; ++j)
            bfr[j] = *reinterpret_cast<const bf16x8*>(&Bs[wc * 64 + j * 16 + lrow][lk]);
#pragma unroll
        for (int i = 0; i < 4; ++i)
#pragma unroll
            for (int j = 0; j < 4; ++j)
                acc[i][j] = __builtin_amdgcn_mfma_f32_16x16x32_bf16(af[i], bfr[j], acc[i][j], 0, 0, 0);
    }

    if (z == 0) {
#pragma unroll
        for (int i = 0; i < 4; ++i) {
            int mbase = m0 + wr * 64 + i * 16 + lkg * 4;
#pragma unroll
            for (int j = 0; j < 4; ++j) {
                int n = n0 + wc * 64 + j * 16 + lrow;
#pragma unroll
                for (int r = 0; r < 4; ++r)
                    Qf[(long)(mbase + r) * EMB + n] = acc[i][j][r];
            }
        }
    } else {
        u16* Out = (z == 1) ? Kb : Vb;
#pragma unroll
        for (int i = 0; i < 4; ++i) {
            int mbase = m0 + wr * 64 + i * 16 + lkg * 4;
#pragma unroll
            for (int j = 0; j < 4; ++j) {
                int n = n0 + wc * 64 + j * 16 + lrow;
                int h = n >> 6, d = n & 63;
#pragma unroll
                for (int r = 0; r < 4; ++r) {
                    int mm = mbase + r;
                    int b = mm >> 12, t = mm & (SEQ - 1);
                    Out[((long)(b * HEADS + h) * SEQ + t) * HD + d] = f2bf(acc[i][j][r]);
                }
            }
        }
    }
}

// ---------------- VALU oracle attention (bisect probe) ----------------------
// One thread per q-row. No MFMA, no shfl, no fragment-layout assumptions.
// grid (SEQ/256, H, B), 256 threads. K/V tiles staged in LDS (broadcast reads).
// QO = fp32 Q in [B,T,C] (d_out); each thread reads its own row fully into
// registers first, writes the same row at the end -> alias-safe.
__global__ void __launch_bounds__(256) attn_valu(
        float* QO, const u16* __restrict__ Kd, const u16* __restrict__ Vd) {
    const int h = blockIdx.y, b = blockIdx.z;
    const int q0 = blockIdx.x * 256;
    const int tid = threadIdx.x;
    const int q = q0 + tid;

    __shared__ u16 Ks[64][72];
    __shared__ u16 Vs[64][72];

    const u16* kb = Kd + (long)(b * HEADS + h) * SEQ * HD;
    const u16* vb = Vd + (long)(b * HEADS + h) * SEQ * HD;

    float qr[64];
    {
        const float* qp = QO + ((long)b * SEQ + q) * EMB + h * HD;
#pragma unroll
        for (int d = 0; d < 64; ++d) qr[d] = qp[d] * 0.125f;   // fold D^-0.5
    }
    float o[64];
#pragma unroll
    for (int d = 0; d < 64; ++d) o[d] = 0.f;
    float m = -1e30f, l = 0.f;

    const int tmax = (q0 + 255) >> 6;             // block-uniform tile bound
    for (int kt = 0; kt <= tmax; ++kt) {
        __syncthreads();
#pragma unroll
        for (int p = 0; p < 2; ++p) {
            int e = tid + p * 256;
            int row = e >> 3, col = (e & 7) * 8;
            *reinterpret_cast<bf16x8*>(&Ks[row][col]) =
                *reinterpret_cast<const bf16x8*>(kb + (long)(kt * 64 + row) * HD + col);
            *reinterpret_cast<bf16x8*>(&Vs[row][col]) =
                *reinterpret_cast<const bf16x8*>(vb + (long)(kt * 64 + row) * HD + col);
        }
        __syncthreads();

        const int kvend = min(63, q - kt * 64);   // causal: kv global <= q
        for (int kv = 0; kv <= kvend; ++kv) {
            // s = qr . K[kv]
            float s = 0.f;
#pragma unroll
            for (int c = 0; c < 8; ++c) {
                uint4 kw = *reinterpret_cast<const uint4*>(&Ks[kv][c * 8]);
                s += qr[c*8+0] * bflo(kw.x) + qr[c*8+1] * bfhi(kw.x)
                   + qr[c*8+2] * bflo(kw.y) + qr[c*8+3] * bfhi(kw.y)
                   + qr[c*8+4] * bflo(kw.z) + qr[c*8+5] * bfhi(kw.z)
                   + qr[c*8+6] * bflo(kw.w) + qr[c*8+7] * bfhi(kw.w);
            }
            // online softmax: rescale only on new max
            if (s > m) {
                float a = __expf(m - s);
                l *= a;
#pragma unroll
                for (int d = 0; d < 64; ++d) o[d] *= a;
                m = s;
            }
            float p = __expf(s - m);
            l += p;
#pragma unroll
            for (int c = 0; c < 8; ++c) {
                uint4 vw = *reinterpret_cast<const uint4*>(&Vs[kv][c * 8]);
                o[c*8+0] += p * bflo(vw.x);  o[c*8+1] += p * bfhi(vw.x);
                o[c*8+2] += p * bflo(vw.y);  o[c*8+3] += p * bfhi(vw.y);
                o[c*8+4] += p * bflo(vw.z);  o[c*8+5] += p * bfhi(vw.z);
                o[c*8+6] += p * bflo(vw.w);  o[c*8+7] += p * bfhi(vw.w);
            }
        }
    }

    const float inv = 1.f / l;
    float* op = QO + ((long)b * SEQ + q) * EMB + h * HD;
#pragma unroll
    for (int d = 0; d < 64; ++d) op[d] = o[d] * inv;
}

// ---------------- launch ----------------------------------------------------
extern "C" void kernel_launch(void* const* d_in, const int* in_sizes, int n_in,
                              void* d_out, int out_size, void* d_ws, size_t ws_size,
                              hipStream_t stream) {
    const float* x  = (const float*)d_in[0];
    const float* wq = (const float*)d_in[1];
    const float* wk = (const float*)d_in[2];
    const float* wv = (const float*)d_in[3];
    float* out = (float*)d_out;

    u16* Kb = (u16*)d_ws;
    u16* Vb = (u16*)((char*)d_ws + (16l << 20));

    gemm_qkv<<<dim3(8, 64, 3), 256, 0, stream>>>(x, wq, wk, wv, out, Kb, Vb);
    attn_valu<<<dim3(SEQ / 256, HEADS, BATCH), 256, 0, stream>>>(out, Kb, Vb);
}

// Round 12
// 960.027 us; speedup vs baseline: 3.8923x; 3.8923x over previous
//
#include <hip/hip_runtime.h>
#include <hip/hip_bf16.h>

typedef unsigned short u16;
typedef __attribute__((ext_vector_type(8))) __bf16 bf16x8;   // MFMA A/B frag (4 VGPRs)
typedef __attribute__((ext_vector_type(4))) float f32x4;     // MFMA C/D frag
typedef __attribute__((ext_vector_type(4))) unsigned short u16x4;

#define EMB   1024
#define HEADS 16
#define HD    64
#define BATCH 2
#define SEQ   4096

static __device__ inline u16 f2bf(float f) {
    __bf16 b = (__bf16)f;                 // RNE fptrunc
    return __builtin_bit_cast(unsigned short, b);
}

// ---------------- fused convert + QKV projection GEMM: Y = X @ W^T ----------
// UNCHANGED (hardware-validated end-to-end by round-6 oracle pass).
__global__ void __launch_bounds__(256) gemm_qkv(
        const float* __restrict__ X,
        const float* __restrict__ Wq, const float* __restrict__ Wk, const float* __restrict__ Wv,
        float* __restrict__ Qf, u16* __restrict__ Kb, u16* __restrict__ Vb) {
    const int z = blockIdx.z;
    const float* W = (z == 0) ? Wq : (z == 1 ? Wk : Wv);

    __shared__ u16 As[128][40];
    __shared__ u16 Bs[128][40];

    const int tid = threadIdx.x, lane = tid & 63, wave = tid >> 6;
    const int wr = wave >> 1, wc = wave & 1;
    const int m0 = blockIdx.y * 128, n0 = blockIdx.x * 128;
    const int lrow = lane & 15, lkg = lane >> 4, lk = lkg * 8;

    f32x4 acc[4][4];
#pragma unroll
    for (int i = 0; i < 4; ++i)
#pragma unroll
        for (int j = 0; j < 4; ++j) acc[i][j] = {};

    for (int k0 = 0; k0 < EMB; k0 += 32) {
        __syncthreads();
#pragma unroll
        for (int p = 0; p < 4; ++p) {
            int c = tid + p * 256;
            int row = c >> 3, col = (c & 7) * 4;
            float4 xa = *reinterpret_cast<const float4*>(X + (long)(m0 + row) * EMB + k0 + col);
            u16x4 xo = { f2bf(xa.x), f2bf(xa.y), f2bf(xa.z), f2bf(xa.w) };
            *reinterpret_cast<u16x4*>(&As[row][col]) = xo;
            float4 wa = *reinterpret_cast<const float4*>(W + (long)(n0 + row) * EMB + k0 + col);
            u16x4 wo = { f2bf(wa.x), f2bf(wa.y), f2bf(wa.z), f2bf(wa.w) };
            *reinterpret_cast<u16x4*>(&Bs[row][col]) = wo;
        }
        __syncthreads();

        bf16x8 af[4], bfr[4];
#pragma unroll
        for (int i = 0; i < 4; ++i)
            af[i] = *reinterpret_cast<const bf16x8*>(&As[wr * 64 + i * 16 + lrow][lk]);
#pragma unroll
        for (int j = 0; j < 4; ++j)
            bfr[j] = *reinterpret_cast<const bf16x8*>(&Bs[wc * 64 + j * 16 + lrow][lk]);
#pragma unroll
        for (int i = 0; i < 4; ++i)
#pragma unroll
            for (int j = 0; j < 4; ++j)
                acc[i][j] = __builtin_amdgcn_mfma_f32_16x16x32_bf16(af[i], bfr[j], acc[i][j], 0, 0, 0);
    }

    if (z == 0) {
#pragma unroll
        for (int i = 0; i < 4; ++i) {
            int mbase = m0 + wr * 64 + i * 16 + lkg * 4;
#pragma unroll
            for (int j = 0; j < 4; ++j) {
                int n = n0 + wc * 64 + j * 16 + lrow;
#pragma unroll
                for (int r = 0; r < 4; ++r)
                    Qf[(long)(mbase + r) * EMB + n] = acc[i][j][r];
            }
        }
    } else {
        u16* Out = (z == 1) ? Kb : Vb;
#pragma unroll
        for (int i = 0; i < 4; ++i) {
            int mbase = m0 + wr * 64 + i * 16 + lkg * 4;
#pragma unroll
            for (int j = 0; j < 4; ++j) {
                int n = n0 + wc * 64 + j * 16 + lrow;
                int h = n >> 6, d = n & 63;
#pragma unroll
                for (int r = 0; r < 4; ++r) {
                    int mm = mbase + r;
                    int b = mm >> 12, t = mm & (SEQ - 1);
                    Out[((long)(b * HEADS + h) * SEQ + t) * HD + d] = f2bf(acc[i][j][r]);
                }
            }
        }
    }
}

// ---------------- MFMA flash attention, NO __bf16 element accesses ----------
// = round-7 structure with two substitutions:
//  (a) Vt staged via uint4 integer unpack (no bf16x8 element extraction)
//  (b) Q staged to LDS (f2bf u16x4 stores), qf read back via bf16x8 pointer
//      reinterpret with the literal GEMM af pattern (no bf16x8 element init)
__global__ void __launch_bounds__(256) attn_fwd(
        float* QO, const u16* __restrict__ Kd, const u16* __restrict__ Vd) {
    const int qt = blockIdx.x, h = blockIdx.y, b = blockIdx.z;
    const int tid = threadIdx.x, lane = tid & 63, wave = tid >> 6;

    __shared__ u16 Qs[64][72];       // Q bf16, pre-scaled by D^-0.5
    __shared__ u16 Ks[64][72];       // K rows: Ks[kv][d]
    __shared__ u16 Vt[64][72];       // V^T:    Vt[d][kv]
    __shared__ u16 Ps[64][72];       // P bf16: Ps[q_local][kv]
    __shared__ float Ss[64][68];     // S fp32
    __shared__ float pmax_s[64][4];
    __shared__ float psum_s[64][4];
    __shared__ float alpha_s[64];
    __shared__ float mnew_s[64];
    __shared__ float linv_s[64];

    const long hb = (long)(b * HEADS + h) * SEQ * HD;
    const u16* kb = Kd + hb;
    const u16* vb = Vd + hb;
    const int lrow = lane & 15, lkg = lane >> 4, lk = lkg * 8;
    const int q0 = qt * 64;
    const int strip = wave * 16;
    const int myrow = tid & 63;           // softmax pass: LDS row
    const int myq   = (tid >> 6) * 16;    // softmax pass: col-quarter base

    // stage Q -> LDS (bf16, x0.125), validated u16x4-store pattern
    {
        const float* qbase = QO + ((long)b * SEQ + q0) * EMB + h * HD;
#pragma unroll
        for (int p = 0; p < 2; ++p) {
            int e = tid + p * 256;
            int row = e >> 3, col = (e & 7) * 8;
            const float* qp = qbase + (long)row * EMB + col;
            float4 x0 = *reinterpret_cast<const float4*>(qp);
            float4 x1 = *reinterpret_cast<const float4*>(qp + 4);
            u16x4 lo = { f2bf(x0.x * 0.125f), f2bf(x0.y * 0.125f), f2bf(x0.z * 0.125f), f2bf(x0.w * 0.125f) };
            u16x4 hi = { f2bf(x1.x * 0.125f), f2bf(x1.y * 0.125f), f2bf(x1.z * 0.125f), f2bf(x1.w * 0.125f) };
            *reinterpret_cast<u16x4*>(&Qs[row][col]) = lo;
            *reinterpret_cast<u16x4*>(&Qs[row][col + 4]) = hi;
        }
    }
    __syncthreads();
    // A-frag read: literal GEMM af pattern (pointer reinterpret, no element ops)
    bf16x8 qf0 = *reinterpret_cast<const bf16x8*>(&Qs[strip + lrow][lk]);
    bf16x8 qf1 = *reinterpret_cast<const bf16x8*>(&Qs[strip + lrow][32 + lk]);

    f32x4 o[4];
#pragma unroll
    for (int i = 0; i < 4; ++i) o[i] = {};
    float m_run = -1e30f, l_run = 0.f;    // row-owner state (valid for tid<64)

    for (int j = 0; j <= qt; ++j) {
        __syncthreads();                  // LDS reuse fence
#pragma unroll
        for (int p = 0; p < 2; ++p) {
            int e = tid + p * 256;
            int row = e >> 3, col = (e & 7) * 8;
            *reinterpret_cast<bf16x8*>(&Ks[row][col]) =
                *reinterpret_cast<const bf16x8*>(kb + (long)(j * 64 + row) * HD + col);
            // Vt staging: uint4 + integer shifts only (THE FIX)
            uint4 vv = *reinterpret_cast<const uint4*>(vb + (long)(j * 64 + row) * HD + col);
            Vt[col + 0][row] = (u16)(vv.x);  Vt[col + 1][row] = (u16)(vv.x >> 16);
            Vt[col + 2][row] = (u16)(vv.y);  Vt[col + 3][row] = (u16)(vv.y >> 16);
            Vt[col + 4][row] = (u16)(vv.z);  Vt[col + 5][row] = (u16)(vv.z >> 16);
            Vt[col + 6][row] = (u16)(vv.w);  Vt[col + 7][row] = (u16)(vv.w >> 16);
        }
        __syncthreads();

        // S = Q K^T (GEMM-isomorphic operand pattern)
        f32x4 s[4];
#pragma unroll
        for (int nt = 0; nt < 4; ++nt) {
            f32x4 a = {};
            a = __builtin_amdgcn_mfma_f32_16x16x32_bf16(
                    qf0, *reinterpret_cast<const bf16x8*>(&Ks[nt * 16 + lrow][lk]), a, 0, 0, 0);
            a = __builtin_amdgcn_mfma_f32_16x16x32_bf16(
                    qf1, *reinterpret_cast<const bf16x8*>(&Ks[nt * 16 + lrow][32 + lk]), a, 0, 0, 0);
            s[nt] = a;
        }

        // C-frag -> LDS scatter: validated C/D attribution
#pragma unroll
        for (int nt = 0; nt < 4; ++nt)
#pragma unroll
            for (int r = 0; r < 4; ++r)
                Ss[strip + lkg * 4 + r][nt * 16 + lrow] = s[nt][r];
        __syncthreads();

        // partial max over 16 cols, causal mask from plain global indices
        {
            const int qglob = q0 + myrow;
            const int kvbase = j * 64 + myq;
            float mx = -1e30f;
#pragma unroll
            for (int c = 0; c < 16; ++c) {
                float sv = (kvbase + c <= qglob) ? Ss[myrow][myq + c] : -1e30f;
                mx = fmaxf(mx, sv);
            }
            pmax_s[myrow][tid >> 6] = mx;
        }
        __syncthreads();

        // row owners: online max update
        if (tid < 64) {
            float tm = fmaxf(fmaxf(pmax_s[tid][0], pmax_s[tid][1]),
                             fmaxf(pmax_s[tid][2], pmax_s[tid][3]));
            float mnew = fmaxf(m_run, tm);
            alpha_s[tid] = __expf(m_run - mnew);
            mnew_s[tid] = mnew;
            m_run = mnew;
        }
        __syncthreads();

        // exp + P write (row-major) + partial sums; all lanes rescale o
        {
            const int qglob = q0 + myrow;
            const int kvbase = j * 64 + myq;
            const float mn = mnew_s[myrow];
            float rs = 0.f;
#pragma unroll
            for (int c = 0; c < 16; ++c) {
                float pv = 0.f;
                if (kvbase + c <= qglob) pv = __expf(Ss[myrow][myq + c] - mn);
                Ps[myrow][myq + c] = f2bf(pv);
                rs += pv;
            }
            psum_s[myrow][tid >> 6] = rs;
        }
#pragma unroll
        for (int dt = 0; dt < 4; ++dt)
#pragma unroll
            for (int r = 0; r < 4; ++r)
                o[dt][r] *= alpha_s[strip + lkg * 4 + r];
        __syncthreads();

        // row owners: online sum update
        if (tid < 64)
            l_run = l_run * alpha_s[tid]
                  + psum_s[tid][0] + psum_s[tid][1] + psum_s[tid][2] + psum_s[tid][3];

        // O += P @ V (validated pointer-reinterpret reads only)
        bf16x8 pf0 = *reinterpret_cast<const bf16x8*>(&Ps[strip + lrow][lk]);
        bf16x8 pf1 = *reinterpret_cast<const bf16x8*>(&Ps[strip + lrow][32 + lk]);
#pragma unroll
        for (int dt = 0; dt < 4; ++dt) {
            o[dt] = __builtin_amdgcn_mfma_f32_16x16x32_bf16(
                        pf0, *reinterpret_cast<const bf16x8*>(&Vt[dt * 16 + lrow][lk]), o[dt], 0, 0, 0);
            o[dt] = __builtin_amdgcn_mfma_f32_16x16x32_bf16(
                        pf1, *reinterpret_cast<const bf16x8*>(&Vt[dt * 16 + lrow][32 + lk]), o[dt], 0, 0, 0);
        }
    }

    __syncthreads();
    if (tid < 64) linv_s[tid] = 1.f / l_run;
    __syncthreads();

    // epilogue (validated attribution)
#pragma unroll
    for (int r = 0; r < 4; ++r) {
        int tg = q0 + strip + lkg * 4 + r;
        float inv = linv_s[strip + lkg * 4 + r];
        float* op = QO + ((long)b * SEQ + tg) * EMB + h * HD;
#pragma unroll
        for (int dt = 0; dt < 4; ++dt)
            op[dt * 16 + lrow] = o[dt][r] * inv;
    }
}

// ---------------- launch ----------------------------------------------------
extern "C" void kernel_launch(void* const* d_in, const int* in_sizes, int n_in,
                              void* d_out, int out_size, void* d_ws, size_t ws_size,
                              hipStream_t stream) {
    const float* x  = (const float*)d_in[0];
    const float* wq = (const float*)d_in[1];
    const float* wk = (const float*)d_in[2];
    const float* wv = (const float*)d_in[3];
    float* out = (float*)d_out;

    u16* Kb = (u16*)d_ws;
    u16* Vb = (u16*)((char*)d_ws + (16l << 20));

    gemm_qkv<<<dim3(8, 64, 3), 256, 0, stream>>>(x, wq, wk, wv, out, Kb, Vb);
    attn_fwd<<<dim3(64, HEADS, BATCH), 256, 0, stream>>>(out, Kb, Vb);
}